// Round 4
// baseline (435.266 us; speedup 1.0000x reference)
//
#include <hip/hip_runtime.h>
#include <hip/hip_bf16.h>

#define NN 8192
#define NE 262144
#define EPSF 1e-9f

typedef __attribute__((ext_vector_type(8))) short short8;
typedef __attribute__((ext_vector_type(4))) float floatx4;

// merged: h0[n][:] = emb[x[n]][:]  AND  deg histogram of dst
__global__ __launch_bounds__(256) void embed_deg_kernel(const int* __restrict__ x,
    const float* __restrict__ emb, float* __restrict__ h0,
    const int* __restrict__ ei, int* __restrict__ deg) {
  int tid = blockIdx.x * 256 + threadIdx.x;
  int n = tid >> 5, j = tid & 31;
  int xi = x[n];
  ((float4*)h0)[(size_t)n * 32 + j] = ((const float4*)emb)[xi * 32 + j];
  atomicAdd(&deg[ei[NE + tid]], 1);
}

// single block: exclusive scan of 8192 degrees -> rowptr[8193], cursor copy
__global__ __launch_bounds__(256) void scan_kernel(const int* __restrict__ deg,
    int* __restrict__ rowptr, int* __restrict__ cursor) {
  __shared__ int wsum[4];
  int t = threadIdx.x;
  int lane = t & 63, w = t >> 6;
  int base = t * 32;
  int local[32];
  int s = 0;
#pragma unroll
  for (int i = 0; i < 32; ++i) { local[i] = deg[base + i]; s += local[i]; }
  int sc = s;
#pragma unroll
  for (int d = 1; d < 64; d <<= 1) {
    int v = __shfl_up(sc, d);
    if (lane >= d) sc += v;
  }
  if (lane == 63) wsum[w] = sc;
  __syncthreads();
  int woff = 0;
  for (int u = 0; u < w; ++u) woff += wsum[u];
  int run = woff + sc - s;
#pragma unroll
  for (int i = 0; i < 32; ++i) {
    rowptr[base + i] = run;
    cursor[base + i] = run;
    run += local[i];
  }
  if (t == 255) rowptr[NN] = run;
}

__global__ __launch_bounds__(256) void scatter_kernel(const int* __restrict__ ei,
    int* __restrict__ cursor, int2* __restrict__ csr) {
  int e = blockIdx.x * 256 + threadIdx.x;
  int s = ei[e], d = ei[NE + e];
  int pos = atomicAdd(&cursor[d], 1);
  csr[pos] = (int2){e, s};
}

// ---- layer 1 fused ----
// wave per node; lane covers cols {lane, lane+64}.
// E1w packed in LDS as lane-adjacent pairs -> ds_read_b64 (16 reads/group not 32).
// Depth-1 pipeline on csr AND ea (ea rows prefetched via uniform loads).
__global__ __launch_bounds__(256) void fused1_kernel(const int* __restrict__ rowptr,
    const int2* __restrict__ csr, const float* __restrict__ ea,
    const float* __restrict__ E1w, const float* __restrict__ E1b,
    const float* __restrict__ W1, const float* __restrict__ b1,
    const float* __restrict__ h0, float* __restrict__ h1) {
  __shared__ float sEp[16 * 128];   // [k][lane][2] = {E1w[k][lane], E1w[k][lane+64]}
  __shared__ float sEb[128];
  __shared__ float st[4][128];
  for (int i = threadIdx.x; i < 16 * 128; i += 256) {
    int k = i >> 7, c = i & 127;
    sEp[k * 128 + (c & 63) * 2 + (c >> 6)] = E1w[i];
  }
  if (threadIdx.x < 128) sEb[threadIdx.x] = E1b[threadIdx.x];
  __syncthreads();
  int lane = threadIdx.x & 63;
  int w = threadIdx.x >> 6;
  int n = blockIdx.x * 4 + w;
  int beg = rowptr[n], end = rowptr[n + 1];
  float acc0 = 0.f, acc1 = 0.f;
  int i = beg;
  int2 pa, pb;
  float4 A0, A1, A2, A3, B0, B1, B2, B3;
  bool have = (i + 2 <= end);
  if (have) {
    pa = csr[i]; pb = csr[i + 1];
    int eA = __builtin_amdgcn_readfirstlane(pa.x);
    int eB = __builtin_amdgcn_readfirstlane(pb.x);
    const float4* qa = (const float4*)(ea + (size_t)eA * 16);
    const float4* qb = (const float4*)(ea + (size_t)eB * 16);
    A0 = qa[0]; A1 = qa[1]; A2 = qa[2]; A3 = qa[3];
    B0 = qb[0]; B1 = qb[1]; B2 = qb[2]; B3 = qb[3];
  }
  while (have) {
    int sA = __builtin_amdgcn_readfirstlane(pa.y);
    int sB = __builtin_amdgcn_readfirstlane(pb.y);
    float hA0 = h0[(size_t)sA * 128 + lane];
    float hA1 = h0[(size_t)sA * 128 + lane + 64];
    float hB0 = h0[(size_t)sB * 128 + lane];
    float hB1 = h0[(size_t)sB * 128 + lane + 64];
    float cA[16] = {A0.x, A0.y, A0.z, A0.w, A1.x, A1.y, A1.z, A1.w,
                    A2.x, A2.y, A2.z, A2.w, A3.x, A3.y, A3.z, A3.w};
    float cB[16] = {B0.x, B0.y, B0.z, B0.w, B1.x, B1.y, B1.z, B1.w,
                    B2.x, B2.y, B2.z, B2.w, B3.x, B3.y, B3.z, B3.w};
    // prefetch next group's csr + ea before the FMA chain
    i += 2;
    have = (i + 2 <= end);
    if (have) {
      pa = csr[i]; pb = csr[i + 1];
      int eA = __builtin_amdgcn_readfirstlane(pa.x);
      int eB = __builtin_amdgcn_readfirstlane(pb.x);
      const float4* qa = (const float4*)(ea + (size_t)eA * 16);
      const float4* qb = (const float4*)(ea + (size_t)eB * 16);
      A0 = qa[0]; A1 = qa[1]; A2 = qa[2]; A3 = qa[3];
      B0 = qb[0]; B1 = qb[1]; B2 = qb[2]; B3 = qb[3];
    }
    float eeA0 = sEb[lane], eeA1 = sEb[lane + 64];
    float eeB0 = eeA0, eeB1 = eeA1;
#pragma unroll
    for (int k = 0; k < 16; ++k) {
      float2 wv = *(const float2*)&sEp[k * 128 + lane * 2];
      eeA0 += cA[k] * wv.x; eeA1 += cA[k] * wv.y;
      eeB0 += cB[k] * wv.x; eeB1 += cB[k] * wv.y;
    }
    float mA0 = hA0 + eeA0, mA1 = hA1 + eeA1;
    float mB0 = hB0 + eeB0, mB1 = hB1 + eeB1;
    acc0 += (mA0 > 0.f ? mA0 : 0.f) + (mB0 > 0.f ? mB0 : 0.f);
    acc1 += (mA1 > 0.f ? mA1 : 0.f) + (mB1 > 0.f ? mB1 : 0.f);
  }
  for (; i < end; ++i) {
    int2 p = csr[i];
    int e = __builtin_amdgcn_readfirstlane(p.x);
    int s = __builtin_amdgcn_readfirstlane(p.y);
    float h_0 = h0[(size_t)s * 128 + lane];
    float h_1 = h0[(size_t)s * 128 + lane + 64];
    const float* eav = ea + (size_t)e * 16;
    float ee0 = sEb[lane], ee1 = sEb[lane + 64];
#pragma unroll
    for (int k = 0; k < 16; ++k) {
      float2 wv = *(const float2*)&sEp[k * 128 + lane * 2];
      ee0 += eav[k] * wv.x;
      ee1 += eav[k] * wv.y;
    }
    float m0 = h_0 + ee0, m1 = h_1 + ee1;
    acc0 += m0 > 0.f ? m0 : 0.f;
    acc1 += m1 > 0.f ? m1 : 0.f;
  }
  st[w][lane]      = (1.0f + EPSF) * h0[(size_t)n * 128 + lane] + acc0;
  st[w][lane + 64] = (1.0f + EPSF) * h0[(size_t)n * 128 + lane + 64] + acc1;
  float o = b1[lane];
#pragma unroll 16
  for (int k = 0; k < 128; ++k) o += st[w][k] * W1[k * 64 + lane];
  h1[(size_t)n * 64 + lane] = o > 0.f ? o : 0.01f * o;
}

// ---- layer 2 fused: 64-wide hidden, E2w packed 2-k-per-read ----
__global__ __launch_bounds__(256) void fused2_kernel(const int* __restrict__ rowptr,
    const int2* __restrict__ csr, const float* __restrict__ ea,
    const float* __restrict__ E2w, const float* __restrict__ E2b,
    const float* __restrict__ W2, const float* __restrict__ b2,
    const float* __restrict__ h1, short* __restrict__ h2) {
  __shared__ float sEp[8 * 128];    // [k2][lane][2] = {E2w[2k2][lane], E2w[2k2+1][lane]}
  __shared__ float sEb[64];
  __shared__ float st[4][64];
  for (int i = threadIdx.x; i < 16 * 64; i += 256) {
    int k = i >> 6, c = i & 63;
    sEp[(k >> 1) * 128 + c * 2 + (k & 1)] = E2w[i];
  }
  if (threadIdx.x < 64) sEb[threadIdx.x] = E2b[threadIdx.x];
  __syncthreads();
  int lane = threadIdx.x & 63;
  int w = threadIdx.x >> 6;
  int n = blockIdx.x * 4 + w;
  int beg = rowptr[n], end = rowptr[n + 1];
  float acc = 0.f;
  int i = beg;
  int2 pa, pb;
  float4 A0, A1, A2, A3, B0, B1, B2, B3;
  bool have = (i + 2 <= end);
  if (have) {
    pa = csr[i]; pb = csr[i + 1];
    int eA = __builtin_amdgcn_readfirstlane(pa.x);
    int eB = __builtin_amdgcn_readfirstlane(pb.x);
    const float4* qa = (const float4*)(ea + (size_t)eA * 16);
    const float4* qb = (const float4*)(ea + (size_t)eB * 16);
    A0 = qa[0]; A1 = qa[1]; A2 = qa[2]; A3 = qa[3];
    B0 = qb[0]; B1 = qb[1]; B2 = qb[2]; B3 = qb[3];
  }
  while (have) {
    int sA = __builtin_amdgcn_readfirstlane(pa.y);
    int sB = __builtin_amdgcn_readfirstlane(pb.y);
    float hA = h1[(size_t)sA * 64 + lane];
    float hB = h1[(size_t)sB * 64 + lane];
    float cA[16] = {A0.x, A0.y, A0.z, A0.w, A1.x, A1.y, A1.z, A1.w,
                    A2.x, A2.y, A2.z, A2.w, A3.x, A3.y, A3.z, A3.w};
    float cB[16] = {B0.x, B0.y, B0.z, B0.w, B1.x, B1.y, B1.z, B1.w,
                    B2.x, B2.y, B2.z, B2.w, B3.x, B3.y, B3.z, B3.w};
    i += 2;
    have = (i + 2 <= end);
    if (have) {
      pa = csr[i]; pb = csr[i + 1];
      int eA = __builtin_amdgcn_readfirstlane(pa.x);
      int eB = __builtin_amdgcn_readfirstlane(pb.x);
      const float4* qa = (const float4*)(ea + (size_t)eA * 16);
      const float4* qb = (const float4*)(ea + (size_t)eB * 16);
      A0 = qa[0]; A1 = qa[1]; A2 = qa[2]; A3 = qa[3];
      B0 = qb[0]; B1 = qb[1]; B2 = qb[2]; B3 = qb[3];
    }
    float eeA = sEb[lane], eeB = eeA;
#pragma unroll
    for (int k2 = 0; k2 < 8; ++k2) {
      float2 wv = *(const float2*)&sEp[k2 * 128 + lane * 2];
      eeA += cA[2 * k2] * wv.x;
      eeA += cA[2 * k2 + 1] * wv.y;
      eeB += cB[2 * k2] * wv.x;
      eeB += cB[2 * k2 + 1] * wv.y;
    }
    float mA = hA + eeA, mB = hB + eeB;
    acc += (mA > 0.f ? mA : 0.f) + (mB > 0.f ? mB : 0.f);
  }
  for (; i < end; ++i) {
    int2 p = csr[i];
    int e = __builtin_amdgcn_readfirstlane(p.x);
    int s = __builtin_amdgcn_readfirstlane(p.y);
    float hv = h1[(size_t)s * 64 + lane];
    const float* eav = ea + (size_t)e * 16;
    float ee = sEb[lane];
#pragma unroll
    for (int k2 = 0; k2 < 8; ++k2) {
      float2 wv = *(const float2*)&sEp[k2 * 128 + lane * 2];
      ee += eav[2 * k2] * wv.x;
      ee += eav[2 * k2 + 1] * wv.y;
    }
    float m = hv + ee;
    acc += m > 0.f ? m : 0.f;
  }
  st[w][lane] = (1.0f + EPSF) * h1[(size_t)n * 64 + lane] + acc;
  int col = lane & 31;
  float o = b2[col];
#pragma unroll 16
  for (int k = 0; k < 64; ++k) o += st[w][k] * W2[k * 32 + col];
  if (lane < 32) {
    unsigned u = __builtin_bit_cast(unsigned, o);
    u += 0x7fffu + ((u >> 16) & 1u);          // round-to-nearest-even
    h2[(size_t)n * 32 + col] = (short)(u >> 16);
  }
}

// out = H2 @ H2^T. One wave -> 16 rows x 64 cols (4 MFMA tiles).
// LDS-transpose epilogue: stores become global_store_dwordx4 covering full
// 256 B-contiguous row chunks (full L2 lines -> no read-for-ownership).
__global__ __launch_bounds__(256) void gemm_kernel(const short* __restrict__ h2,
    float* __restrict__ out) {
  __shared__ float tile[4][16 * 68];          // wave-private 16 x 68(pad)
  int wid = (blockIdx.x * 256 + threadIdx.x) >> 6;
  int lane = threadIdx.x & 63;
  int w = threadIdx.x >> 6;
  int cg = wid & 127;
  int rt = wid >> 7;
  int r = lane & 15, q = lane >> 4;
  short8 afrag = *(const short8*)(h2 + ((rt * 16 + r) * 32 + q * 8));
  floatx4 acc[4];
#pragma unroll
  for (int t = 0; t < 4; ++t) {
    short8 bfrag = *(const short8*)(h2 + ((cg * 64 + t * 16 + r) * 32 + q * 8));
    floatx4 z = {0.f, 0.f, 0.f, 0.f};
    acc[t] = __builtin_amdgcn_mfma_f32_16x16x32_bf16(afrag, bfrag, z, 0, 0, 0);
  }
  float* T = tile[w];
#pragma unroll
  for (int t = 0; t < 4; ++t)
#pragma unroll
    for (int reg = 0; reg < 4; ++reg)
      T[(q * 4 + reg) * 68 + t * 16 + r] = acc[t][reg];
  // same-wave LDS RAW (wave-private region): compiler orders via lgkmcnt
#pragma unroll
  for (int j = 0; j < 4; ++j) {
    float4 v = *(const float4*)&T[(j * 4 + q) * 68 + r * 4];
    *(float4*)&out[(size_t)(rt * 16 + j * 4 + q) * NN + cg * 64 + r * 4] = v;
  }
}

extern "C" void kernel_launch(void* const* d_in, const int* in_sizes, int n_in,
                              void* d_out, int out_size, void* d_ws, size_t ws_size,
                              hipStream_t stream) {
  const int*   x   = (const int*)d_in[0];
  const int*   ei  = (const int*)d_in[1];
  const float* ea  = (const float*)d_in[2];
  const float* emb = (const float*)d_in[3];
  const float* W1  = (const float*)d_in[4];
  const float* b1  = (const float*)d_in[5];
  const float* E1w = (const float*)d_in[6];
  const float* E1b = (const float*)d_in[7];
  const float* W2  = (const float*)d_in[8];
  const float* b2  = (const float*)d_in[9];
  const float* E2w = (const float*)d_in[10];
  const float* E2b = (const float*)d_in[11];

  float* ws     = (float*)d_ws;
  float* h0     = ws;                        // 4 MB
  float* h1     = ws + 1048576;              // 2 MB
  short* h2     = (short*)(ws + 1572864);    // 512 KB
  int*   deg    = (int*)(ws + 1703936);
  int*   rowptr = (int*)(ws + 1712128);
  int*   cursor = (int*)(ws + 1720832);
  int2*  csr    = (int2*)(ws + 1729024);     // 2 MB

  hipMemsetAsync(deg, 0, NN * sizeof(int), stream);
  embed_deg_kernel<<<1024, 256, 0, stream>>>(x, emb, h0, ei, deg);
  scan_kernel<<<1, 256, 0, stream>>>(deg, rowptr, cursor);
  scatter_kernel<<<1024, 256, 0, stream>>>(ei, cursor, csr);
  fused1_kernel<<<2048, 256, 0, stream>>>(rowptr, csr, ea, E1w, E1b, W1, b1, h0, h1);
  fused2_kernel<<<2048, 256, 0, stream>>>(rowptr, csr, ea, E2w, E2b, W2, b2, h1, h2);
  gemm_kernel<<<16384, 256, 0, stream>>>(h2, (float*)d_out);
}

// Round 5
// 383.048 us; speedup vs baseline: 1.1363x; 1.1363x over previous
//
#include <hip/hip_runtime.h>
#include <hip/hip_bf16.h>

#define NN 8192
#define NE 262144
#define EPSF 1e-9f

typedef __attribute__((ext_vector_type(8))) short short8;
typedef __attribute__((ext_vector_type(4))) float floatx4;

// xoff[n] = x[n]*128  AND  deg histogram of dst (NE threads)
__global__ __launch_bounds__(256) void xoff_deg_kernel(const int* __restrict__ x,
    int* __restrict__ xoff, const int* __restrict__ ei, int* __restrict__ deg) {
  int tid = blockIdx.x * 256 + threadIdx.x;
  if (tid < NN) xoff[tid] = x[tid] * 128;
  atomicAdd(&deg[ei[NE + tid]], 1);
}

// single block: exclusive scan of 8192 degrees -> rowptr[8193], cursor copy
__global__ __launch_bounds__(256) void scan_kernel(const int* __restrict__ deg,
    int* __restrict__ rowptr, int* __restrict__ cursor) {
  __shared__ int wsum[4];
  int t = threadIdx.x;
  int lane = t & 63, w = t >> 6;
  int base = t * 32;
  int local[32];
  int s = 0;
#pragma unroll
  for (int i = 0; i < 32; ++i) { local[i] = deg[base + i]; s += local[i]; }
  int sc = s;
#pragma unroll
  for (int d = 1; d < 64; d <<= 1) {
    int v = __shfl_up(sc, d);
    if (lane >= d) sc += v;
  }
  if (lane == 63) wsum[w] = sc;
  __syncthreads();
  int woff = 0;
  for (int u = 0; u < w; ++u) woff += wsum[u];
  int run = woff + sc - s;
#pragma unroll
  for (int i = 0; i < 32; ++i) {
    rowptr[base + i] = run;
    cursor[base + i] = run;
    run += local[i];
  }
  if (t == 255) rowptr[NN] = run;
}

// csr record: {e, s, xoff[s], 0} -- fused1 gathers emb directly via .z
__global__ __launch_bounds__(256) void scatter_kernel(const int* __restrict__ ei,
    const int* __restrict__ xoff, int* __restrict__ cursor, int4* __restrict__ csr) {
  int e = blockIdx.x * 256 + threadIdx.x;
  int s = ei[e], d = ei[NE + e];
  int xo = xoff[s];
  int pos = atomicAdd(&cursor[d], 1);
  csr[pos] = (int4){e, s, xo, 0};
}

// ---- layer 1 fused: per-node gather + edge MLP + aggregate + node GEMM + leaky ----
// wave per node; lane covers cols {lane, lane+64}.
// Gathers from emb (10 KB, L1-resident) via csr.z = x[src]*128 -- h0 never built.
// csr broadcast-load for group g+1 prefetched before group g's FMA chain.
__global__ __launch_bounds__(256) void fused1_kernel(const int* __restrict__ rowptr,
    const int4* __restrict__ csr, const float* __restrict__ ea,
    const float* __restrict__ E1w, const float* __restrict__ E1b,
    const float* __restrict__ W1, const float* __restrict__ b1,
    const int* __restrict__ xoff, const float* __restrict__ emb,
    float* __restrict__ h1) {
  __shared__ float sE[16 * 128];
  __shared__ float sEb[128];
  __shared__ float st[4][128];
  for (int i = threadIdx.x; i < 16 * 128; i += 256) sE[i] = E1w[i];
  if (threadIdx.x < 128) sEb[threadIdx.x] = E1b[threadIdx.x];
  __syncthreads();
  int lane = threadIdx.x & 63;
  int w = threadIdx.x >> 6;
  int n = blockIdx.x * 4 + w;                 // 2048 blocks * 4 waves = 8192 nodes
  int beg = rowptr[n], end = rowptr[n + 1];
  int xon = xoff[n];
  float acc0 = 0.f, acc1 = 0.f;
  int i = beg;
  int4 pa, pb;
  bool have = (i + 2 <= end);
  if (have) { pa = csr[i]; pb = csr[i + 1]; }
  while (have) {
    int eA = __builtin_amdgcn_readfirstlane(pa.x);
    int oA = __builtin_amdgcn_readfirstlane(pa.z);
    int eB = __builtin_amdgcn_readfirstlane(pb.x);
    int oB = __builtin_amdgcn_readfirstlane(pb.z);
    // current group's gathers: emb is L1-resident (10 KB)
    float hA0 = emb[oA + lane];
    float hA1 = emb[oA + lane + 64];
    float hB0 = emb[oB + lane];
    float hB1 = emb[oB + lane + 64];
    // prefetch next group's csr (16 B broadcast) before the FMA chain
    i += 2;
    have = (i + 2 <= end);
    if (have) { pa = csr[i]; pb = csr[i + 1]; }
    const float* eaA = ea + (size_t)eA * 16;
    const float* eaB = ea + (size_t)eB * 16;
    float eeA0 = sEb[lane], eeA1 = sEb[lane + 64];
    float eeB0 = eeA0, eeB1 = eeA1;
#pragma unroll
    for (int k = 0; k < 16; ++k) {
      float w0 = sE[k * 128 + lane], w1 = sE[k * 128 + lane + 64];
      eeA0 += eaA[k] * w0; eeA1 += eaA[k] * w1;
      eeB0 += eaB[k] * w0; eeB1 += eaB[k] * w1;
    }
    float mA0 = hA0 + eeA0, mA1 = hA1 + eeA1;
    float mB0 = hB0 + eeB0, mB1 = hB1 + eeB1;
    acc0 += (mA0 > 0.f ? mA0 : 0.f) + (mB0 > 0.f ? mB0 : 0.f);
    acc1 += (mA1 > 0.f ? mA1 : 0.f) + (mB1 > 0.f ? mB1 : 0.f);
  }
  for (; i < end; ++i) {
    int4 p = csr[i];
    int e = __builtin_amdgcn_readfirstlane(p.x);
    int o = __builtin_amdgcn_readfirstlane(p.z);
    float h_0 = emb[o + lane];
    float h_1 = emb[o + lane + 64];
    const float* eav = ea + (size_t)e * 16;
    float ee0 = sEb[lane], ee1 = sEb[lane + 64];
#pragma unroll
    for (int k = 0; k < 16; ++k) {
      ee0 += eav[k] * sE[k * 128 + lane];
      ee1 += eav[k] * sE[k * 128 + lane + 64];
    }
    float m0 = h_0 + ee0, m1 = h_1 + ee1;
    acc0 += m0 > 0.f ? m0 : 0.f;
    acc1 += m1 > 0.f ? m1 : 0.f;
  }
  st[w][lane]      = (1.0f + EPSF) * emb[xon + lane] + acc0;
  st[w][lane + 64] = (1.0f + EPSF) * emb[xon + lane + 64] + acc1;
  // same-wave LDS RAW: DS ops issue in order within a wave, no barrier needed
  float o = b1[lane];
#pragma unroll 16
  for (int k = 0; k < 128; ++k) o += st[w][k] * W1[k * 64 + lane];
  h1[(size_t)n * 64 + lane] = o > 0.f ? o : 0.01f * o;
}

// ---- layer 2 fused: same structure, 64-wide hidden, 32-wide bf16 output ----
__global__ __launch_bounds__(256) void fused2_kernel(const int* __restrict__ rowptr,
    const int4* __restrict__ csr, const float* __restrict__ ea,
    const float* __restrict__ E2w, const float* __restrict__ E2b,
    const float* __restrict__ W2, const float* __restrict__ b2,
    const float* __restrict__ h1, short* __restrict__ h2) {
  __shared__ float sE[16 * 64];
  __shared__ float sEb[64];
  __shared__ float st[4][64];
  for (int i = threadIdx.x; i < 16 * 64; i += 256) sE[i] = E2w[i];
  if (threadIdx.x < 64) sEb[threadIdx.x] = E2b[threadIdx.x];
  __syncthreads();
  int lane = threadIdx.x & 63;
  int w = threadIdx.x >> 6;
  int n = blockIdx.x * 4 + w;
  int beg = rowptr[n], end = rowptr[n + 1];
  float acc = 0.f;
  int i = beg;
  int4 pa, pb;
  bool have = (i + 2 <= end);
  if (have) { pa = csr[i]; pb = csr[i + 1]; }
  while (have) {
    int eA = __builtin_amdgcn_readfirstlane(pa.x);
    int sA = __builtin_amdgcn_readfirstlane(pa.y);
    int eB = __builtin_amdgcn_readfirstlane(pb.x);
    int sB = __builtin_amdgcn_readfirstlane(pb.y);
    float hA = h1[(size_t)sA * 64 + lane];
    float hB = h1[(size_t)sB * 64 + lane];
    i += 2;
    have = (i + 2 <= end);
    if (have) { pa = csr[i]; pb = csr[i + 1]; }
    const float* eaA = ea + (size_t)eA * 16;
    const float* eaB = ea + (size_t)eB * 16;
    float eeA = sEb[lane], eeB = eeA;
#pragma unroll
    for (int k = 0; k < 16; ++k) {
      float wv = sE[k * 64 + lane];
      eeA += eaA[k] * wv;
      eeB += eaB[k] * wv;
    }
    float mA = hA + eeA, mB = hB + eeB;
    acc += (mA > 0.f ? mA : 0.f) + (mB > 0.f ? mB : 0.f);
  }
  for (; i < end; ++i) {
    int4 p = csr[i];
    int e = __builtin_amdgcn_readfirstlane(p.x);
    int s = __builtin_amdgcn_readfirstlane(p.y);
    float hv = h1[(size_t)s * 64 + lane];
    const float* eav = ea + (size_t)e * 16;
    float ee = sEb[lane];
#pragma unroll
    for (int k = 0; k < 16; ++k) ee += eav[k] * sE[k * 64 + lane];
    float m = hv + ee;
    acc += m > 0.f ? m : 0.f;
  }
  st[w][lane] = (1.0f + EPSF) * h1[(size_t)n * 64 + lane] + acc;
  int col = lane & 31;
  float o = b2[col];
#pragma unroll 16
  for (int k = 0; k < 64; ++k) o += st[w][k] * W2[k * 32 + col];
  if (lane < 32) {
    unsigned u = __builtin_bit_cast(unsigned, o);
    u += 0x7fffu + ((u >> 16) & 1u);          // round-to-nearest-even
    h2[(size_t)n * 32 + col] = (short)(u >> 16);
  }
}

// out = H2 @ H2^T, H2: 8192x32 bf16. One wave -> 16 rows x 64 cols (4 MFMA tiles).
// A frag: A[m=lane&15][k=(lane>>4)*8 + j]; B frag: B[k][n=lane&15] (same load pattern
// from H2 since B = H2^T). C/D: col=lane&15, row=(lane>>4)*4+reg.
__global__ __launch_bounds__(256) void gemm_kernel(const short* __restrict__ h2,
    float* __restrict__ out) {
  int wid = (blockIdx.x * 256 + threadIdx.x) >> 6;  // 65536 waves
  int lane = threadIdx.x & 63;
  int cg = wid & 127;    // col group of 64
  int rt = wid >> 7;     // row tile of 16
  int r = lane & 15, q = lane >> 4;
  short8 afrag = *(const short8*)(h2 + ((rt * 16 + r) * 32 + q * 8));
  floatx4 acc[4];
#pragma unroll
  for (int t = 0; t < 4; ++t) {
    short8 bfrag = *(const short8*)(h2 + ((cg * 64 + t * 16 + r) * 32 + q * 8));
    floatx4 z = {0.f, 0.f, 0.f, 0.f};
    acc[t] = __builtin_amdgcn_mfma_f32_16x16x32_bf16(afrag, bfrag, z, 0, 0, 0);
  }
  int row_base = rt * 16 + q * 4;
  int col_base = cg * 64 + r;
#pragma unroll
  for (int t = 0; t < 4; ++t)
#pragma unroll
    for (int reg = 0; reg < 4; ++reg)
      out[(size_t)(row_base + reg) * NN + col_base + t * 16] = acc[t][reg];
}

extern "C" void kernel_launch(void* const* d_in, const int* in_sizes, int n_in,
                              void* d_out, int out_size, void* d_ws, size_t ws_size,
                              hipStream_t stream) {
  const int*   x   = (const int*)d_in[0];
  const int*   ei  = (const int*)d_in[1];
  const float* ea  = (const float*)d_in[2];
  const float* emb = (const float*)d_in[3];
  const float* W1  = (const float*)d_in[4];
  const float* b1  = (const float*)d_in[5];
  const float* E1w = (const float*)d_in[6];
  const float* E1b = (const float*)d_in[7];
  const float* W2  = (const float*)d_in[8];
  const float* b2  = (const float*)d_in[9];
  const float* E2w = (const float*)d_in[10];
  const float* E2b = (const float*)d_in[11];

  float* ws     = (float*)d_ws;
  float* h1     = ws;                        // 8192*64 = 524288 f (2 MB)
  short* h2     = (short*)(ws + 524288);     // 8192*32 bf16
  int*   deg    = (int*)(ws + 589824);       // 8192
  int*   rowptr = (int*)(ws + 598016);       // 8193 (padded)
  int*   cursor = (int*)(ws + 606720);       // 8192
  int*   xoff   = (int*)(ws + 614912);       // 8192
  int4*  csr    = (int4*)(ws + 623104);      // NE int4 (4 MB)

  hipMemsetAsync(deg, 0, NN * sizeof(int), stream);
  xoff_deg_kernel<<<1024, 256, 0, stream>>>(x, xoff, ei, deg);
  scan_kernel<<<1, 256, 0, stream>>>(deg, rowptr, cursor);
  scatter_kernel<<<1024, 256, 0, stream>>>(ei, xoff, cursor, csr);
  fused1_kernel<<<2048, 256, 0, stream>>>(rowptr, csr, ea, E1w, E1b, W1, b1, xoff, emb, h1);
  fused2_kernel<<<2048, 256, 0, stream>>>(rowptr, csr, ea, E2w, E2b, W2, b2, h1, h2);
  gemm_kernel<<<16384, 256, 0, stream>>>(h2, (float*)d_out);
}